// Round 4
// baseline (362.624 us; speedup 1.0000x reference)
//
#include <hip/hip_runtime.h>
#include <hip/hip_bf16.h>

typedef __bf16 bf16;
typedef __bf16 bf16x8 __attribute__((ext_vector_type(8)));
typedef float  floatx4 __attribute__((ext_vector_type(4)));

#define EPSF      1e-7f
#define MAXNORM   0.99999f   // (1 - 1e-5) / sqrt(C), C = 1

__device__ __forceinline__ float sane(float x) {
    return (fabsf(x) < 1e30f) ? x : 0.0f;
}

// rowwise scale implementing logmap0(proj(expmap0(h))) = scale(||h||) * h
__device__ __forceinline__ float hyp_scale(float ss) {
    float n  = sqrtf(ss);
    float nh = fmaxf(n, EPSF);            // clip in expmap0
    float s1 = tanhf(nh) / nh;            // x = s1 * h
    float nx = s1 * n;                    // ||x||
    if (nx > MAXNORM) { s1 *= MAXNORM / nx; nx = MAXNORM; }   // proj
    float nx2 = fmaxf(nx, EPSF);          // clip in logmap0
    return (atanhf(nx2) / nx2) * s1;
}

__device__ __forceinline__ bf16x8 cvt8(float4 a, float4 b) {
    bf16x8 r;
    r[0] = (bf16)a.x; r[1] = (bf16)a.y; r[2] = (bf16)a.z; r[3] = (bf16)a.w;
    r[4] = (bf16)b.x; r[5] = (bf16)b.y; r[6] = (bf16)b.z; r[7] = (bf16)b.w;
    return r;
}

// XOR-granule swizzle for a [128][128] bf16 LDS tile (16B granules)
__device__ __forceinline__ int sw128(int row, int k) {
    return row * 128 + (((k >> 3) ^ (row & 15)) << 3) + (k & 7);
}
// same for a [128][64] tile
__device__ __forceinline__ int sw64(int row, int k) {
    return row * 64 + (((k >> 3) ^ (row & 7)) << 3) + (k & 7);
}

// ---------------------------------------------------------------------------
// Thin GEMM: Y[128 rows x 128] = X[128x128] @ B + epilogue, per block.
// MODE 0: EMBED — X fp32 global, W fp32 [out][in] (no transpose), rowscale -> Y(bf16)
// MODE 1: MSG   — X bf16 ws, W fp32 [in][out] (transpose), +bias -> Y(bf16) and YT(mT)
// MODE 2: AGG   — X bf16 ws, W fp32 [in][out] (transpose), +bias, +m, relu, rowscale -> Y(bf16)
// MODE 3: PROJ  — X bf16 ws, W fp32 [out][in] (no transpose), +bias, *mask -> Yf(fp32)
// ---------------------------------------------------------------------------
template <int MODE>
__global__ __launch_bounds__(256) void gemm128(
    const void* __restrict__ Xv, const float* __restrict__ W,
    const float* __restrict__ bias, const bf16* __restrict__ MaddB,
    const float* __restrict__ MaddF,
    bf16* __restrict__ Y, bf16* __restrict__ YT, float* __restrict__ Yf)
{
    __shared__ __align__(16) bf16 Xs[128 * 128];
    __shared__ __align__(16) bf16 Ws[128 * 128];
    const int tid = threadIdx.x;
    const int bx  = blockIdx.x;

    // ---- stage X tile (16384 elements = 2048 bf16x8 granules) ----
    if (MODE == 0) {
        const float4* Xg = reinterpret_cast<const float4*>(
            (const float*)Xv + (size_t)bx * 16384);
        #pragma unroll
        for (int i = 0; i < 8; ++i) {
            int g = tid + i * 256;                 // granule 0..2047
            int row = g >> 4, gc = g & 15;
            float4 v0 = Xg[2 * g], v1 = Xg[2 * g + 1];
            *reinterpret_cast<bf16x8*>(&Xs[row * 128 + ((gc ^ (row & 15)) << 3)]) = cvt8(v0, v1);
        }
    } else {
        const bf16x8* Xg = reinterpret_cast<const bf16x8*>(
            (const bf16*)Xv + (size_t)bx * 16384);
        #pragma unroll
        for (int i = 0; i < 8; ++i) {
            int g = tid + i * 256;
            int row = g >> 4, gc = g & 15;
            bf16x8 v = Xg[g];
            *reinterpret_cast<bf16x8*>(&Xs[row * 128 + ((gc ^ (row & 15)) << 3)]) = v;
        }
    }
    // ---- stage W as Ws[n][k] ----
    if (MODE == 1 || MODE == 2) {
        // W stored [k][n] fp32 -> transpose + cvt
        const int c0 = (tid & 15) * 8;
        #pragma unroll
        for (int rr = 0; rr < 8; ++rr) {
            int r = (tid >> 4) * 8 + rr;           // k index 0..127
            const float4* p = reinterpret_cast<const float4*>(W + r * 128 + c0);
            float4 v0 = p[0], v1 = p[1];
            float vv[8] = {v0.x, v0.y, v0.z, v0.w, v1.x, v1.y, v1.z, v1.w};
            #pragma unroll
            for (int j = 0; j < 8; ++j) {
                int n = c0 + j;
                Ws[n * 128 + (((r >> 3) ^ (n & 15)) << 3) + (r & 7)] = (bf16)vv[j];
            }
        }
    } else {
        // W stored [n][k] fp32 already
        const float4* Wg = reinterpret_cast<const float4*>(W);
        #pragma unroll
        for (int i = 0; i < 8; ++i) {
            int g = tid + i * 256;
            int row = g >> 4, gc = g & 15;
            float4 v0 = Wg[2 * g], v1 = Wg[2 * g + 1];
            *reinterpret_cast<bf16x8*>(&Ws[row * 128 + ((gc ^ (row & 15)) << 3)]) = cvt8(v0, v1);
        }
    }
    __syncthreads();

    const int lane = tid & 63;
    const int wv   = tid >> 6;
    const int n16  = lane & 15;
    const int quad = lane >> 4;
    const int rbase = wv * 32;        // wave covers 32 rows x 128 cols

    floatx4 acc[2][8];
    #pragma unroll
    for (int a = 0; a < 2; ++a)
        #pragma unroll
        for (int b = 0; b < 8; ++b) acc[a][b] = (floatx4){0.f, 0.f, 0.f, 0.f};

    #pragma unroll
    for (int kc = 0; kc < 4; ++kc) {
        int k0 = kc * 32 + quad * 8;
        bf16x8 a0 = *reinterpret_cast<const bf16x8*>(&Xs[sw128(rbase + n16, k0)]);
        bf16x8 a1 = *reinterpret_cast<const bf16x8*>(&Xs[sw128(rbase + 16 + n16, k0)]);
        #pragma unroll
        for (int ct = 0; ct < 8; ++ct) {
            bf16x8 b = *reinterpret_cast<const bf16x8*>(&Ws[sw128(ct * 16 + n16, k0)]);
            acc[0][ct] = __builtin_amdgcn_mfma_f32_16x16x32_bf16(a0, b, acc[0][ct], 0, 0, 0);
            acc[1][ct] = __builtin_amdgcn_mfma_f32_16x16x32_bf16(a1, b, acc[1][ct], 0, 0, 0);
        }
    }

    float bv[8];
    #pragma unroll
    for (int ct = 0; ct < 8; ++ct)
        bv[ct] = (MODE != 0) ? sane(bias[ct * 16 + n16]) : 0.0f;

    #pragma unroll
    for (int rt = 0; rt < 2; ++rt) {
        #pragma unroll
        for (int r = 0; r < 4; ++r) {
            const int lrow = rbase + rt * 16 + quad * 4 + r;
            const size_t grow = (size_t)bx * 128 + lrow;
            float u[8];
            #pragma unroll
            for (int ct = 0; ct < 8; ++ct) {
                u[ct] = acc[rt][ct][r] + bv[ct];
                if (MODE == 2)
                    u[ct] = fmaxf(u[ct] + (float)MaddB[grow * 128 + ct * 16 + n16], 0.0f);
                u[ct] = sane(u[ct]);
            }
            if (MODE == 0 || MODE == 2) {
                float ss = 0.f;
                #pragma unroll
                for (int ct = 0; ct < 8; ++ct) ss += u[ct] * u[ct];
                #pragma unroll
                for (int off = 1; off < 16; off <<= 1) ss += __shfl_xor(ss, off);
                float sc = hyp_scale(sane(ss));
                #pragma unroll
                for (int ct = 0; ct < 8; ++ct) u[ct] *= sc;
            }
            if (MODE == 3) {
                float mk = sane(MaddF[grow]);
                #pragma unroll
                for (int ct = 0; ct < 8; ++ct)
                    Yf[grow * 128 + ct * 16 + n16] = sane(u[ct] * mk);
            } else {
                #pragma unroll
                for (int ct = 0; ct < 8; ++ct) {
                    bf16 o = (bf16)sane(u[ct]);
                    Y[grow * 128 + ct * 16 + n16] = o;
                    if (MODE == 1) {
                        size_t bb = grow >> 10, node = grow & 1023;
                        YT[((bb << 7) + ct * 16 + n16) * 1024 + node] = o;
                    }
                }
            }
        }
    }
}

// ---------------------------------------------------------------------------
// Fat GEMM: agg0[b] = Adj[b] @ m[b]   ([1024x1024] x [1024x128] per batch)
// Adj is fp32 global; mT is bf16 workspace [b][dim][node].
// ---------------------------------------------------------------------------
__global__ __launch_bounds__(256) void adjmm(
    const float* __restrict__ Adj, const bf16* __restrict__ mT,
    bf16* __restrict__ agg0)
{
    __shared__ __align__(16) bf16 As[128 * 64];
    __shared__ __align__(16) bf16 Bs[128 * 64];
    const int tid = threadIdx.x;
    const int b   = blockIdx.x >> 3;
    const int mt  = blockIdx.x & 7;
    const float* Ag = Adj + ((size_t)b << 20) + ((size_t)mt << 17);
    const bf16*  Bg = mT  + ((size_t)b << 17);

    const int lane = tid & 63, wv = tid >> 6;
    const int n16 = lane & 15, quad = lane >> 4;
    const int wr = (wv >> 1) * 64, wc = (wv & 1) * 64;   // wave = 64x64 subtile

    floatx4 acc[4][4];
    #pragma unroll
    for (int a = 0; a < 4; ++a)
        #pragma unroll
        for (int c = 0; c < 4; ++c) acc[a][c] = (floatx4){0.f, 0.f, 0.f, 0.f};

    for (int kk = 0; kk < 16; ++kk) {
        const int k0 = kk * 64;
        #pragma unroll
        for (int i = 0; i < 4; ++i) {
            int g = tid + i * 256;            // granule 0..1023 (128 rows x 8)
            int row = g >> 3, gc = g & 7;
            const float4* pa = reinterpret_cast<const float4*>(
                Ag + (size_t)row * 1024 + k0 + gc * 8);
            float4 a0 = pa[0], a1 = pa[1];
            *reinterpret_cast<bf16x8*>(&As[row * 64 + ((gc ^ (row & 7)) << 3)]) = cvt8(a0, a1);
            bf16x8 vb = *reinterpret_cast<const bf16x8*>(Bg + (size_t)row * 1024 + k0 + gc * 8);
            *reinterpret_cast<bf16x8*>(&Bs[row * 64 + ((gc ^ (row & 7)) << 3)]) = vb;
        }
        __syncthreads();
        #pragma unroll
        for (int kc = 0; kc < 2; ++kc) {
            const int ko = kc * 32 + quad * 8;
            bf16x8 a[4], bb[4];
            #pragma unroll
            for (int rt = 0; rt < 4; ++rt)
                a[rt] = *reinterpret_cast<const bf16x8*>(&As[sw64(wr + rt * 16 + n16, ko)]);
            #pragma unroll
            for (int ct = 0; ct < 4; ++ct)
                bb[ct] = *reinterpret_cast<const bf16x8*>(&Bs[sw64(wc + ct * 16 + n16, ko)]);
            #pragma unroll
            for (int rt = 0; rt < 4; ++rt)
                #pragma unroll
                for (int ct = 0; ct < 4; ++ct)
                    acc[rt][ct] = __builtin_amdgcn_mfma_f32_16x16x32_bf16(a[rt], bb[ct], acc[rt][ct], 0, 0, 0);
        }
        __syncthreads();
    }

    const size_t outBase = ((size_t)b * 1024 + (size_t)mt * 128) * 128;
    #pragma unroll
    for (int rt = 0; rt < 4; ++rt) {
        #pragma unroll
        for (int r = 0; r < 4; ++r) {
            int lrow = wr + rt * 16 + quad * 4 + r;
            #pragma unroll
            for (int ct = 0; ct < 4; ++ct)
                agg0[outBase + (size_t)lrow * 128 + wc + ct * 16 + n16] = (bf16)sane(acc[rt][ct][r]);
        }
    }
}

extern "C" void kernel_launch(void* const* d_in, const int* in_sizes, int n_in,
                              void* d_out, int out_size, void* d_ws, size_t ws_size,
                              hipStream_t stream)
{
    const float* X    = (const float*)d_in[0];   // [32,1024,128] fp32
    const float* Adj  = (const float*)d_in[1];   // [32,1024,1024] fp32
    const float* Mask = (const float*)d_in[2];   // [32,1024,1] fp32
    const float* Wemb = (const float*)d_in[3];   // [128,128] (out,in)
    const float* Wmsg = (const float*)d_in[4];   // [2,128,128] (in,out)
    const float* bmsg = (const float*)d_in[5];   // [2,128]
    const float* Wagg = (const float*)d_in[6];   // [2,128,128] (in,out)
    const float* bagg = (const float*)d_in[7];   // [2,128]
    const float* Wprj = (const float*)d_in[8];   // [128,128] (out,in)
    const float* bprj = (const float*)d_in[9];   // [128]
    float* out = (float*)d_out;

    // 3-buffer rotation (bf16), 24 MB total footprint.
    const size_t BN = 32768;                     // 32*1024
    bf16* buf0 = (bf16*)d_ws;                    // [BN,128] each
    bf16* buf1 = buf0 + BN * 128;
    bf16* buf2 = buf1 + BN * 128;

    dim3 grid(256), blk(256);

    // t0 -> buf0
    gemm128<0><<<grid, blk, 0, stream>>>(X, Wemb, nullptr, nullptr, nullptr,
                                         buf0, nullptr, nullptr);
    // layer 0: t=buf0; m->buf1, mT->buf2; agg->buf0; t1->buf2
    gemm128<1><<<grid, blk, 0, stream>>>(buf0, Wmsg, bmsg, nullptr, nullptr,
                                         buf1, buf2, nullptr);
    adjmm<<<grid, blk, 0, stream>>>(Adj, buf2, buf0);
    gemm128<2><<<grid, blk, 0, stream>>>(buf0, Wagg, bagg, buf1, nullptr,
                                         buf2, nullptr, nullptr);
    // layer 1: t=buf2; m->buf1, mT->buf0; agg->buf2; t2->buf0
    gemm128<1><<<grid, blk, 0, stream>>>(buf2, Wmsg + 16384, bmsg + 128, nullptr, nullptr,
                                         buf1, buf0, nullptr);
    adjmm<<<grid, blk, 0, stream>>>(Adj, buf0, buf2);
    gemm128<2><<<grid, blk, 0, stream>>>(buf2, Wagg + 16384, bagg + 128, buf1, nullptr,
                                         buf0, nullptr, nullptr);
    // proj: t2=buf0 -> out (fp32)
    gemm128<3><<<grid, blk, 0, stream>>>(buf0, Wprj, bprj, nullptr, Mask,
                                         nullptr, nullptr, out);
}

// Round 5
// 304.019 us; speedup vs baseline: 1.1928x; 1.1928x over previous
//
#include <hip/hip_runtime.h>
#include <hip/hip_bf16.h>

typedef __bf16 bf16;
typedef __bf16 bf16x8 __attribute__((ext_vector_type(8)));
typedef float  floatx4 __attribute__((ext_vector_type(4)));

#define EPSF    1e-7f
#define MAXNORM 0.99999f   // (1 - 1e-5) / sqrt(C), C = 1
#define TS_LD   136        // padded leading dim for LDS intermediate tile

// rowwise scale implementing logmap0(proj(expmap0(h))) = scale(||h||) * h
__device__ __forceinline__ float hyp_scale(float ss) {
    float n  = sqrtf(ss);
    float nh = fmaxf(n, EPSF);
    float s1 = tanhf(nh) / nh;
    float nx = s1 * n;
    if (nx > MAXNORM) { s1 *= MAXNORM / nx; nx = MAXNORM; }
    float nx2 = fmaxf(nx, EPSF);
    return (atanhf(nx2) / nx2) * s1;
}

__device__ __forceinline__ bf16x8 cvt8(float4 a, float4 b) {
    bf16x8 r;
    r[0] = (bf16)a.x; r[1] = (bf16)a.y; r[2] = (bf16)a.z; r[3] = (bf16)a.w;
    r[4] = (bf16)b.x; r[5] = (bf16)b.y; r[6] = (bf16)b.z; r[7] = (bf16)b.w;
    return r;
}

// XOR-granule swizzles (16B granules, conflict-free MFMA frag reads)
__device__ __forceinline__ int sw128(int row, int k) {
    return row * 128 + (((k >> 3) ^ (row & 15)) << 3) + (k & 7);
}
__device__ __forceinline__ int sw64(int row, int k) {
    return row * 64 + (((k >> 3) ^ (row & 7)) << 3) + (k & 7);
}

// ---------------------------------------------------------------------------
// K1: embed + msg0 fused.  Per block: 128 rows.
//   h = X@Wemb^T ; t0 = rowscale(h) ; m0 = t0@Wmsg0 + b  -> M (rows), MT ([b][dim][node])
// ---------------------------------------------------------------------------
__global__ __launch_bounds__(256) void embed_msg(
    const float* __restrict__ X, const float* __restrict__ Wemb,
    const float* __restrict__ Wmsg, const float* __restrict__ bmsg,
    bf16* __restrict__ M, bf16* __restrict__ MT)
{
    __shared__ __align__(16) bf16 Xs[128 * 128];
    __shared__ __align__(16) bf16 Ws[128 * 128];
    __shared__ __align__(16) bf16 W2[128 * 128];
    __shared__ __align__(16) bf16 Ts[128 * TS_LD];
    const int tid = threadIdx.x, bx = blockIdx.x;

    // stage X fp32->bf16 (2048 granules)
    {
        const float4* Xg = reinterpret_cast<const float4*>(X + (size_t)bx * 16384);
        #pragma unroll
        for (int i = 0; i < 8; ++i) {
            int g = tid + i * 256, row = g >> 4, gc = g & 15;
            float4 v0 = Xg[2 * g], v1 = Xg[2 * g + 1];
            *reinterpret_cast<bf16x8*>(&Xs[row * 128 + ((gc ^ (row & 15)) << 3)]) = cvt8(v0, v1);
        }
    }
    // stage Wemb [out][in] direct -> Ws[n][k]
    {
        const float4* Wg = reinterpret_cast<const float4*>(Wemb);
        #pragma unroll
        for (int i = 0; i < 8; ++i) {
            int g = tid + i * 256, row = g >> 4, gc = g & 15;
            float4 v0 = Wg[2 * g], v1 = Wg[2 * g + 1];
            *reinterpret_cast<bf16x8*>(&Ws[row * 128 + ((gc ^ (row & 15)) << 3)]) = cvt8(v0, v1);
        }
    }
    // stage Wmsg [in][out] transposed -> W2[n][k]
    {
        const int c0 = (tid & 15) * 8;
        #pragma unroll
        for (int rr = 0; rr < 8; ++rr) {
            int r = (tid >> 4) * 8 + rr;
            const float4* p = reinterpret_cast<const float4*>(Wmsg + r * 128 + c0);
            float4 v0 = p[0], v1 = p[1];
            float vv[8] = {v0.x, v0.y, v0.z, v0.w, v1.x, v1.y, v1.z, v1.w};
            #pragma unroll
            for (int j = 0; j < 8; ++j) {
                int n = c0 + j;
                W2[n * 128 + (((r >> 3) ^ (n & 15)) << 3) + (r & 7)] = (bf16)vv[j];
            }
        }
    }
    __syncthreads();

    const int lane = tid & 63, wv = tid >> 6, n16 = lane & 15, quad = lane >> 4;
    const int rbase = wv * 32;

    // phase 1: h = X @ Wemb^T
    floatx4 acc[2][8];
    #pragma unroll
    for (int a = 0; a < 2; ++a)
        #pragma unroll
        for (int c = 0; c < 8; ++c) acc[a][c] = (floatx4){0.f, 0.f, 0.f, 0.f};
    #pragma unroll
    for (int kc = 0; kc < 4; ++kc) {
        int k0 = kc * 32 + quad * 8;
        bf16x8 a0 = *reinterpret_cast<const bf16x8*>(&Xs[sw128(rbase + n16, k0)]);
        bf16x8 a1 = *reinterpret_cast<const bf16x8*>(&Xs[sw128(rbase + 16 + n16, k0)]);
        #pragma unroll
        for (int ct = 0; ct < 8; ++ct) {
            bf16x8 b = *reinterpret_cast<const bf16x8*>(&Ws[sw128(ct * 16 + n16, k0)]);
            acc[0][ct] = __builtin_amdgcn_mfma_f32_16x16x32_bf16(a0, b, acc[0][ct], 0, 0, 0);
            acc[1][ct] = __builtin_amdgcn_mfma_f32_16x16x32_bf16(a1, b, acc[1][ct], 0, 0, 0);
        }
    }
    // rowscale -> t0 into Ts (padded)
    #pragma unroll
    for (int rt = 0; rt < 2; ++rt) {
        #pragma unroll
        for (int r = 0; r < 4; ++r) {
            int row = rbase + rt * 16 + quad * 4 + r;
            float u[8], ss = 0.f;
            #pragma unroll
            for (int ct = 0; ct < 8; ++ct) { u[ct] = acc[rt][ct][r]; ss += u[ct] * u[ct]; }
            #pragma unroll
            for (int off = 1; off < 16; off <<= 1) ss += __shfl_xor(ss, off);
            float sc = hyp_scale(ss);
            #pragma unroll
            for (int ct = 0; ct < 8; ++ct)
                Ts[row * TS_LD + ct * 16 + n16] = (bf16)(u[ct] * sc);
        }
    }
    __syncthreads();

    // phase 2: m0 = t0 @ Wmsg + b
    floatx4 acc2[2][8];
    #pragma unroll
    for (int a = 0; a < 2; ++a)
        #pragma unroll
        for (int c = 0; c < 8; ++c) acc2[a][c] = (floatx4){0.f, 0.f, 0.f, 0.f};
    #pragma unroll
    for (int kc = 0; kc < 4; ++kc) {
        int k0 = kc * 32 + quad * 8;
        bf16x8 a0 = *reinterpret_cast<const bf16x8*>(&Ts[(rbase + n16) * TS_LD + k0]);
        bf16x8 a1 = *reinterpret_cast<const bf16x8*>(&Ts[(rbase + 16 + n16) * TS_LD + k0]);
        #pragma unroll
        for (int ct = 0; ct < 8; ++ct) {
            bf16x8 b = *reinterpret_cast<const bf16x8*>(&W2[sw128(ct * 16 + n16, k0)]);
            acc2[0][ct] = __builtin_amdgcn_mfma_f32_16x16x32_bf16(a0, b, acc2[0][ct], 0, 0, 0);
            acc2[1][ct] = __builtin_amdgcn_mfma_f32_16x16x32_bf16(a1, b, acc2[1][ct], 0, 0, 0);
        }
    }
    float bv[8];
    #pragma unroll
    for (int ct = 0; ct < 8; ++ct) bv[ct] = bmsg[ct * 16 + n16];
    #pragma unroll
    for (int rt = 0; rt < 2; ++rt) {
        #pragma unroll
        for (int r = 0; r < 4; ++r) {
            int lrow = rbase + rt * 16 + quad * 4 + r;
            size_t grow = (size_t)bx * 128 + lrow;
            #pragma unroll
            for (int ct = 0; ct < 8; ++ct) {
                bf16 o = (bf16)(acc2[rt][ct][r] + bv[ct]);
                M[grow * 128 + ct * 16 + n16] = o;
                MT[((grow >> 10) * 128 + ct * 16 + n16) * 1024 + (grow & 1023)] = o;
            }
        }
    }
}

// ---------------------------------------------------------------------------
// K2/K3: adjmm + aggW + relu + rowscale + (msg | proj) fused.
// 512 threads, 8 waves. Block = [128 nodes] x full K=1024 of one batch.
// XCD swizzle: b = bid&31, mt = bid>>5 (same-batch tiles share an XCD's L2).
// ---------------------------------------------------------------------------
template <int LAST>
__global__ __launch_bounds__(512) void adj_fused(
    const float* __restrict__ Adj, const bf16* __restrict__ MT,
    const bf16* __restrict__ Mprev,
    const float* __restrict__ Wagg, const float* __restrict__ bagg,
    const float* __restrict__ W2f,  const float* __restrict__ b2,
    const float* __restrict__ Mask,
    bf16* __restrict__ Mout, bf16* __restrict__ MTout, float* __restrict__ Out)
{
    // 64 KB: K-loop double-buffered As/Bs; reused for Wa/W2 in the epilogue
    __shared__ __align__(16) bf16 smem[4 * 128 * 64];
    __shared__ __align__(16) bf16 Ts[128 * TS_LD];
    bf16* As0 = smem;
    bf16* As1 = smem + 128 * 64;
    bf16* Bs0 = smem + 2 * 128 * 64;
    bf16* Bs1 = smem + 3 * 128 * 64;

    const int tid = threadIdx.x, bid = blockIdx.x;
    const int mt = bid >> 5, b = bid & 31;
    const float* Ag = Adj + ((size_t)b << 20) + ((size_t)mt << 17);
    const bf16*  Bg = MT  + ((size_t)b << 17);

    const int lane = tid & 63, wv = tid >> 6, n16 = lane & 15, quad = lane >> 4;
    const int wr = (wv >> 2) * 64, wc = (wv & 3) * 32;   // wave = 64 rows x 32 dims

    floatx4 acc[4][2];
    #pragma unroll
    for (int a = 0; a < 4; ++a)
        #pragma unroll
        for (int c = 0; c < 2; ++c) acc[a][c] = (floatx4){0.f, 0.f, 0.f, 0.f};

    // register prefetch buffers (2 granules/thread of A and B)
    float4 pa[2][2]; bf16x8 pb[2];
    auto load_regs = [&](int kk) {
        #pragma unroll
        for (int i = 0; i < 2; ++i) {
            int g = tid + i * 512, row = g >> 3, gc = g & 7;
            const float4* pA = reinterpret_cast<const float4*>(
                Ag + (size_t)row * 1024 + kk * 64 + gc * 8);
            pa[i][0] = pA[0]; pa[i][1] = pA[1];
            pb[i] = *reinterpret_cast<const bf16x8*>(Bg + (size_t)row * 1024 + kk * 64 + gc * 8);
        }
    };
    auto store_lds = [&](bf16* A, bf16* B) {
        #pragma unroll
        for (int i = 0; i < 2; ++i) {
            int g = tid + i * 512, row = g >> 3, gc = g & 7;
            *reinterpret_cast<bf16x8*>(&A[row * 64 + ((gc ^ (row & 7)) << 3)]) = cvt8(pa[i][0], pa[i][1]);
            *reinterpret_cast<bf16x8*>(&B[row * 64 + ((gc ^ (row & 7)) << 3)]) = pb[i];
        }
    };

    load_regs(0);
    store_lds(As0, Bs0);
    for (int kk = 0; kk < 16; ++kk) {
        bf16* Acur = (kk & 1) ? As1 : As0;
        bf16* Bcur = (kk & 1) ? Bs1 : Bs0;
        bf16* Anxt = (kk & 1) ? As0 : As1;
        bf16* Bnxt = (kk & 1) ? Bs0 : Bs1;
        if (kk < 15) load_regs(kk + 1);
        __syncthreads();
        #pragma unroll
        for (int kc = 0; kc < 2; ++kc) {
            int ko = kc * 32 + quad * 8;
            bf16x8 a[4], bb[2];
            #pragma unroll
            for (int rt = 0; rt < 4; ++rt)
                a[rt] = *reinterpret_cast<const bf16x8*>(&Acur[sw64(wr + rt * 16 + n16, ko)]);
            #pragma unroll
            for (int ct = 0; ct < 2; ++ct)
                bb[ct] = *reinterpret_cast<const bf16x8*>(&Bcur[sw64(wc + ct * 16 + n16, ko)]);
            #pragma unroll
            for (int rt = 0; rt < 4; ++rt)
                #pragma unroll
                for (int ct = 0; ct < 2; ++ct)
                    acc[rt][ct] = __builtin_amdgcn_mfma_f32_16x16x32_bf16(a[rt], bb[ct], acc[rt][ct], 0, 0, 0);
        }
        if (kk < 15) store_lds(Anxt, Bnxt);
    }
    __syncthreads();   // all K-loop LDS traffic done; smem is free for reuse

    // write agg C-tiles into padded Ts
    #pragma unroll
    for (int rt = 0; rt < 4; ++rt)
        #pragma unroll
        for (int ct = 0; ct < 2; ++ct)
            #pragma unroll
            for (int r = 0; r < 4; ++r) {
                int row = wr + rt * 16 + quad * 4 + r, col = wc + ct * 16 + n16;
                Ts[row * TS_LD + col] = (bf16)acc[rt][ct][r];
            }

    // stage Wagg [in][out] transposed -> Wa; W2: LAST? [out][in] direct : transposed
    bf16* Wa = smem;               // 128*128 sw128
    bf16* W2 = smem + 128 * 128;   // 128*128 sw128
    {
        const int c0 = (tid & 15) * 8;
        #pragma unroll
        for (int rr = 0; rr < 4; ++rr) {
            int r = (tid >> 4) * 4 + rr;
            const float4* p = reinterpret_cast<const float4*>(Wagg + r * 128 + c0);
            float4 v0 = p[0], v1 = p[1];
            float vv[8] = {v0.x, v0.y, v0.z, v0.w, v1.x, v1.y, v1.z, v1.w};
            #pragma unroll
            for (int j = 0; j < 8; ++j) {
                int n = c0 + j;
                Wa[n * 128 + (((r >> 3) ^ (n & 15)) << 3) + (r & 7)] = (bf16)vv[j];
            }
        }
    }
    if (LAST) {
        const float4* Wg = reinterpret_cast<const float4*>(W2f);
        #pragma unroll
        for (int i = 0; i < 4; ++i) {
            int g = tid + i * 512, row = g >> 4, gc = g & 15;
            float4 v0 = Wg[2 * g], v1 = Wg[2 * g + 1];
            *reinterpret_cast<bf16x8*>(&W2[row * 128 + ((gc ^ (row & 15)) << 3)]) = cvt8(v0, v1);
        }
    } else {
        const int c0 = (tid & 15) * 8;
        #pragma unroll
        for (int rr = 0; rr < 4; ++rr) {
            int r = (tid >> 4) * 4 + rr;
            const float4* p = reinterpret_cast<const float4*>(W2f + r * 128 + c0);
            float4 v0 = p[0], v1 = p[1];
            float vv[8] = {v0.x, v0.y, v0.z, v0.w, v1.x, v1.y, v1.z, v1.w};
            #pragma unroll
            for (int j = 0; j < 8; ++j) {
                int n = c0 + j;
                W2[n * 128 + (((r >> 3) ^ (n & 15)) << 3) + (r & 7)] = (bf16)vv[j];
            }
        }
    }
    __syncthreads();

    // phase 3: u = relu(agg@Wagg + bagg + m_prev); t = rowscale(u) -> Ts (in place)
    const int rbase = wv * 16;                 // wave = 16 rows x 128 cols
    const size_t growbase = (size_t)b * 1024 + (size_t)mt * 128;
    floatx4 acc2[8];
    #pragma unroll
    for (int c = 0; c < 8; ++c) acc2[c] = (floatx4){0.f, 0.f, 0.f, 0.f};
    #pragma unroll
    for (int kc = 0; kc < 4; ++kc) {
        int k0 = kc * 32 + quad * 8;
        bf16x8 a = *reinterpret_cast<const bf16x8*>(&Ts[(rbase + n16) * TS_LD + k0]);
        #pragma unroll
        for (int ct = 0; ct < 8; ++ct) {
            bf16x8 bb = *reinterpret_cast<const bf16x8*>(&Wa[sw128(ct * 16 + n16, k0)]);
            acc2[ct] = __builtin_amdgcn_mfma_f32_16x16x32_bf16(a, bb, acc2[ct], 0, 0, 0);
        }
    }
    {
        float bva[8];
        #pragma unroll
        for (int ct = 0; ct < 8; ++ct) bva[ct] = bagg[ct * 16 + n16];
        #pragma unroll
        for (int r = 0; r < 4; ++r) {
            int row = rbase + quad * 4 + r;
            size_t grow = growbase + row;
            float u[8], ss = 0.f;
            #pragma unroll
            for (int ct = 0; ct < 8; ++ct) {
                u[ct] = fmaxf(acc2[ct][r] + bva[ct] + (float)Mprev[grow * 128 + ct * 16 + n16], 0.f);
                ss += u[ct] * u[ct];
            }
            #pragma unroll
            for (int off = 1; off < 16; off <<= 1) ss += __shfl_xor(ss, off);
            float sc = hyp_scale(ss);
            #pragma unroll
            for (int ct = 0; ct < 8; ++ct)
                Ts[row * TS_LD + ct * 16 + n16] = (bf16)(u[ct] * sc);
        }
    }
    // same-wave rows only: per-wave DS ordering makes a barrier unnecessary here

    // phase 4: t @ W2 (+b2); LAST: *mask -> fp32 Out; else -> Mout/MTout
    floatx4 acc3[8];
    #pragma unroll
    for (int c = 0; c < 8; ++c) acc3[c] = (floatx4){0.f, 0.f, 0.f, 0.f};
    #pragma unroll
    for (int kc = 0; kc < 4; ++kc) {
        int k0 = kc * 32 + quad * 8;
        bf16x8 a = *reinterpret_cast<const bf16x8*>(&Ts[(rbase + n16) * TS_LD + k0]);
        #pragma unroll
        for (int ct = 0; ct < 8; ++ct) {
            bf16x8 bb = *reinterpret_cast<const bf16x8*>(&W2[sw128(ct * 16 + n16, k0)]);
            acc3[ct] = __builtin_amdgcn_mfma_f32_16x16x32_bf16(a, bb, acc3[ct], 0, 0, 0);
        }
    }
    float bv2[8];
    #pragma unroll
    for (int ct = 0; ct < 8; ++ct) bv2[ct] = b2[ct * 16 + n16];
    #pragma unroll
    for (int r = 0; r < 4; ++r) {
        int row = rbase + quad * 4 + r;
        size_t grow = growbase + row;
        if (LAST) {
            float mk = Mask[grow];
            #pragma unroll
            for (int ct = 0; ct < 8; ++ct)
                Out[grow * 128 + ct * 16 + n16] = (acc3[ct][r] + bv2[ct]) * mk;
        } else {
            #pragma unroll
            for (int ct = 0; ct < 8; ++ct) {
                bf16 o = (bf16)(acc3[ct][r] + bv2[ct]);
                Mout[grow * 128 + ct * 16 + n16] = o;
                MTout[((grow >> 10) * 128 + ct * 16 + n16) * 1024 + (grow & 1023)] = o;
            }
        }
    }
}

extern "C" void kernel_launch(void* const* d_in, const int* in_sizes, int n_in,
                              void* d_out, int out_size, void* d_ws, size_t ws_size,
                              hipStream_t stream)
{
    const float* X    = (const float*)d_in[0];   // [32,1024,128]
    const float* Adj  = (const float*)d_in[1];   // [32,1024,1024]
    const float* Mask = (const float*)d_in[2];   // [32,1024,1]
    const float* Wemb = (const float*)d_in[3];   // [128,128] (out,in)
    const float* Wmsg = (const float*)d_in[4];   // [2,128,128] (in,out)
    const float* bmsg = (const float*)d_in[5];   // [2,128]
    const float* Wagg = (const float*)d_in[6];   // [2,128,128] (in,out)
    const float* bagg = (const float*)d_in[7];   // [2,128]
    const float* Wprj = (const float*)d_in[8];   // [128,128] (out,in)
    const float* bprj = (const float*)d_in[9];   // [128]
    float* out = (float*)d_out;

    const size_t BN = 32768;
    bf16* m0  = (bf16*)d_ws;         // [BN,128]
    bf16* m0T = m0  + BN * 128;      // [32,128,1024]
    bf16* m1  = m0T + BN * 128;      // [BN,128]
    bf16* m1T = m1  + BN * 128;      // [32,128,1024]

    embed_msg<<<256, 256, 0, stream>>>(X, Wemb, Wmsg, bmsg, m0, m0T);
    adj_fused<0><<<256, 512, 0, stream>>>(Adj, m0T, m0, Wagg, bagg,
                                          Wmsg + 16384, bmsg + 128, nullptr,
                                          m1, m1T, nullptr);
    adj_fused<1><<<256, 512, 0, stream>>>(Adj, m1T, m1, Wagg + 16384, bagg + 128,
                                          Wprj, bprj, Mask,
                                          nullptr, nullptr, out);
}

// Round 6
// 303.768 us; speedup vs baseline: 1.1938x; 1.0008x over previous
//
#include <hip/hip_runtime.h>
#include <hip/hip_bf16.h>

typedef __bf16 bf16;
typedef __bf16 bf16x8 __attribute__((ext_vector_type(8)));
typedef float  floatx4 __attribute__((ext_vector_type(4)));

#define EPSF    1e-7f
#define MAXNORM 0.99999f   // (1 - 1e-5) / sqrt(C), C = 1
#define TS_LD   136        // padded leading dim for LDS intermediate tile

// rowwise scale implementing logmap0(proj(expmap0(h))) = scale(||h||) * h
__device__ __forceinline__ float hyp_scale(float ss) {
    float n  = sqrtf(ss);
    float nh = fmaxf(n, EPSF);
    float s1 = tanhf(nh) / nh;
    float nx = s1 * n;
    if (nx > MAXNORM) { s1 *= MAXNORM / nx; nx = MAXNORM; }
    float nx2 = fmaxf(nx, EPSF);
    return (atanhf(nx2) / nx2) * s1;
}

__device__ __forceinline__ bf16x8 cvt8(float4 a, float4 b) {
    bf16x8 r;
    r[0] = (bf16)a.x; r[1] = (bf16)a.y; r[2] = (bf16)a.z; r[3] = (bf16)a.w;
    r[4] = (bf16)b.x; r[5] = (bf16)b.y; r[6] = (bf16)b.z; r[7] = (bf16)b.w;
    return r;
}

// XOR-granule swizzles (16B granules, conflict-free MFMA frag reads)
__device__ __forceinline__ int sw128(int row, int k) {
    return row * 128 + (((k >> 3) ^ (row & 15)) << 3) + (k & 7);
}
__device__ __forceinline__ int sw64(int row, int k) {
    return row * 64 + (((k >> 3) ^ (row & 7)) << 3) + (k & 7);
}

// ---------------------------------------------------------------------------
// K1: embed + msg0 fused.  Per block: 128 rows.
//   h = X@Wemb^T ; t0 = rowscale(h) ; m0 = t0@Wmsg0 + b  -> M (rows), MT ([b][dim][node])
// ---------------------------------------------------------------------------
__global__ __launch_bounds__(256) void embed_msg(
    const float* __restrict__ X, const float* __restrict__ Wemb,
    const float* __restrict__ Wmsg, const float* __restrict__ bmsg,
    bf16* __restrict__ M, bf16* __restrict__ MT)
{
    __shared__ __align__(16) bf16 Xs[128 * 128];
    __shared__ __align__(16) bf16 Ws[128 * 128];
    __shared__ __align__(16) bf16 W2[128 * 128];
    __shared__ __align__(16) bf16 Ts[128 * TS_LD];
    const int tid = threadIdx.x, bx = blockIdx.x;

    // stage X fp32->bf16 (2048 granules)
    {
        const float4* Xg = reinterpret_cast<const float4*>(X + (size_t)bx * 16384);
        #pragma unroll
        for (int i = 0; i < 8; ++i) {
            int g = tid + i * 256, row = g >> 4, gc = g & 15;
            float4 v0 = Xg[2 * g], v1 = Xg[2 * g + 1];
            *reinterpret_cast<bf16x8*>(&Xs[row * 128 + ((gc ^ (row & 15)) << 3)]) = cvt8(v0, v1);
        }
    }
    // stage Wemb [out][in] direct -> Ws[n][k]
    {
        const float4* Wg = reinterpret_cast<const float4*>(Wemb);
        #pragma unroll
        for (int i = 0; i < 8; ++i) {
            int g = tid + i * 256, row = g >> 4, gc = g & 15;
            float4 v0 = Wg[2 * g], v1 = Wg[2 * g + 1];
            *reinterpret_cast<bf16x8*>(&Ws[row * 128 + ((gc ^ (row & 15)) << 3)]) = cvt8(v0, v1);
        }
    }
    // stage Wmsg [in][out] transposed -> W2[n][k]
    {
        const int c0 = (tid & 15) * 8;
        #pragma unroll
        for (int rr = 0; rr < 8; ++rr) {
            int r = (tid >> 4) * 8 + rr;
            const float4* p = reinterpret_cast<const float4*>(Wmsg + r * 128 + c0);
            float4 v0 = p[0], v1 = p[1];
            float vv[8] = {v0.x, v0.y, v0.z, v0.w, v1.x, v1.y, v1.z, v1.w};
            #pragma unroll
            for (int j = 0; j < 8; ++j) {
                int n = c0 + j;
                W2[n * 128 + (((r >> 3) ^ (n & 15)) << 3) + (r & 7)] = (bf16)vv[j];
            }
        }
    }
    __syncthreads();

    const int lane = tid & 63, wv = tid >> 6, n16 = lane & 15, quad = lane >> 4;
    const int rbase = wv * 32;

    // phase 1: h = X @ Wemb^T
    floatx4 acc[2][8];
    #pragma unroll
    for (int a = 0; a < 2; ++a)
        #pragma unroll
        for (int c = 0; c < 8; ++c) acc[a][c] = (floatx4){0.f, 0.f, 0.f, 0.f};
    #pragma unroll
    for (int kc = 0; kc < 4; ++kc) {
        int k0 = kc * 32 + quad * 8;
        bf16x8 a0 = *reinterpret_cast<const bf16x8*>(&Xs[sw128(rbase + n16, k0)]);
        bf16x8 a1 = *reinterpret_cast<const bf16x8*>(&Xs[sw128(rbase + 16 + n16, k0)]);
        #pragma unroll
        for (int ct = 0; ct < 8; ++ct) {
            bf16x8 b = *reinterpret_cast<const bf16x8*>(&Ws[sw128(ct * 16 + n16, k0)]);
            acc[0][ct] = __builtin_amdgcn_mfma_f32_16x16x32_bf16(a0, b, acc[0][ct], 0, 0, 0);
            acc[1][ct] = __builtin_amdgcn_mfma_f32_16x16x32_bf16(a1, b, acc[1][ct], 0, 0, 0);
        }
    }
    // rowscale -> t0 into Ts (padded)
    #pragma unroll
    for (int rt = 0; rt < 2; ++rt) {
        #pragma unroll
        for (int r = 0; r < 4; ++r) {
            int row = rbase + rt * 16 + quad * 4 + r;
            float u[8], ss = 0.f;
            #pragma unroll
            for (int ct = 0; ct < 8; ++ct) { u[ct] = acc[rt][ct][r]; ss += u[ct] * u[ct]; }
            #pragma unroll
            for (int off = 1; off < 16; off <<= 1) ss += __shfl_xor(ss, off);
            float sc = hyp_scale(ss);
            #pragma unroll
            for (int ct = 0; ct < 8; ++ct)
                Ts[row * TS_LD + ct * 16 + n16] = (bf16)(u[ct] * sc);
        }
    }
    __syncthreads();

    // phase 2: m0 = t0 @ Wmsg + b
    floatx4 acc2[2][8];
    #pragma unroll
    for (int a = 0; a < 2; ++a)
        #pragma unroll
        for (int c = 0; c < 8; ++c) acc2[a][c] = (floatx4){0.f, 0.f, 0.f, 0.f};
    #pragma unroll
    for (int kc = 0; kc < 4; ++kc) {
        int k0 = kc * 32 + quad * 8;
        bf16x8 a0 = *reinterpret_cast<const bf16x8*>(&Ts[(rbase + n16) * TS_LD + k0]);
        bf16x8 a1 = *reinterpret_cast<const bf16x8*>(&Ts[(rbase + 16 + n16) * TS_LD + k0]);
        #pragma unroll
        for (int ct = 0; ct < 8; ++ct) {
            bf16x8 b = *reinterpret_cast<const bf16x8*>(&W2[sw128(ct * 16 + n16, k0)]);
            acc2[0][ct] = __builtin_amdgcn_mfma_f32_16x16x32_bf16(a0, b, acc2[0][ct], 0, 0, 0);
            acc2[1][ct] = __builtin_amdgcn_mfma_f32_16x16x32_bf16(a1, b, acc2[1][ct], 0, 0, 0);
        }
    }
    float bv[8];
    #pragma unroll
    for (int ct = 0; ct < 8; ++ct) bv[ct] = bmsg[ct * 16 + n16];
    #pragma unroll
    for (int rt = 0; rt < 2; ++rt) {
        #pragma unroll
        for (int r = 0; r < 4; ++r) {
            int lrow = rbase + rt * 16 + quad * 4 + r;
            size_t grow = (size_t)bx * 128 + lrow;
            #pragma unroll
            for (int ct = 0; ct < 8; ++ct) {
                bf16 o = (bf16)(acc2[rt][ct][r] + bv[ct]);
                M[grow * 128 + ct * 16 + n16] = o;
                MT[((grow >> 10) * 128 + ct * 16 + n16) * 1024 + (grow & 1023)] = o;
            }
        }
    }
}

// ---------------------------------------------------------------------------
// K2/K3: adjmm + aggW + relu + rowscale + (msg | proj) fused.
// 512 threads, 8 waves. Block = [128 nodes] x full K=1024 of one batch.
// K-loop is PHASE-STAGGERED per block (kk0) so the chip-wide address stream
// doesn't hit the same 256B-per-4KB window on every step (channel conflicts).
// ---------------------------------------------------------------------------
template <int LAST>
__global__ __launch_bounds__(512) void adj_fused(
    const float* __restrict__ Adj, const bf16* __restrict__ MT,
    const bf16* __restrict__ Mprev,
    const float* __restrict__ Wagg, const float* __restrict__ bagg,
    const float* __restrict__ W2f,  const float* __restrict__ b2,
    const float* __restrict__ Mask,
    bf16* __restrict__ Mout, bf16* __restrict__ MTout, float* __restrict__ Out)
{
    // 64 KB: K-loop double-buffered As/Bs; reused for Wa/W2 in the epilogue
    __shared__ __align__(16) bf16 smem[4 * 128 * 64];
    __shared__ __align__(16) bf16 Ts[128 * TS_LD];
    bf16* As0 = smem;
    bf16* As1 = smem + 128 * 64;
    bf16* Bs0 = smem + 2 * 128 * 64;
    bf16* Bs1 = smem + 3 * 128 * 64;

    const int tid = threadIdx.x, bid = blockIdx.x;
    const int mt = bid >> 5, b = bid & 31;
    const float* Ag = Adj + ((size_t)b << 20) + ((size_t)mt << 17);
    const bf16*  Bg = MT  + ((size_t)b << 17);

    const int lane = tid & 63, wv = tid >> 6, n16 = lane & 15, quad = lane >> 4;
    const int wr = (wv >> 2) * 64, wc = (wv & 3) * 32;   // wave = 64 rows x 32 dims

    // per-block K phase stagger
    const int kk0 = (bid * 5 + (bid >> 5)) & 15;

    floatx4 acc[4][2];
    #pragma unroll
    for (int a = 0; a < 4; ++a)
        #pragma unroll
        for (int c = 0; c < 2; ++c) acc[a][c] = (floatx4){0.f, 0.f, 0.f, 0.f};

    // register prefetch buffers (2 granules/thread of A and B)
    float4 pa[2][2]; bf16x8 pb[2];
    auto load_regs = [&](int kk) {
        #pragma unroll
        for (int i = 0; i < 2; ++i) {
            int g = tid + i * 512, row = g >> 3, gc = g & 7;
            const float4* pA = reinterpret_cast<const float4*>(
                Ag + (size_t)row * 1024 + kk * 64 + gc * 8);
            pa[i][0] = pA[0]; pa[i][1] = pA[1];
            pb[i] = *reinterpret_cast<const bf16x8*>(Bg + (size_t)row * 1024 + kk * 64 + gc * 8);
        }
    };
    auto store_lds = [&](bf16* A, bf16* B) {
        #pragma unroll
        for (int i = 0; i < 2; ++i) {
            int g = tid + i * 512, row = g >> 3, gc = g & 7;
            *reinterpret_cast<bf16x8*>(&A[row * 64 + ((gc ^ (row & 7)) << 3)]) = cvt8(pa[i][0], pa[i][1]);
            *reinterpret_cast<bf16x8*>(&B[row * 64 + ((gc ^ (row & 7)) << 3)]) = pb[i];
        }
    };

    // prologue: stage logical step kk0 into buffer 0
    load_regs(kk0);
    store_lds(As0, Bs0);
    for (int p = 0; p < 16; ++p) {
        bf16* Acur = (p & 1) ? As1 : As0;
        bf16* Bcur = (p & 1) ? Bs1 : Bs0;
        bf16* Anxt = (p & 1) ? As0 : As1;
        bf16* Bnxt = (p & 1) ? Bs0 : Bs1;
        __syncthreads();                         // staged buffer visible
        if (p < 15) load_regs((p + 1 + kk0) & 15);  // issue AFTER barrier -> overlaps MFMA
        #pragma unroll
        for (int kc = 0; kc < 2; ++kc) {
            int ko = kc * 32 + quad * 8;
            bf16x8 a[4], bb[2];
            #pragma unroll
            for (int rt = 0; rt < 4; ++rt)
                a[rt] = *reinterpret_cast<const bf16x8*>(&Acur[sw64(wr + rt * 16 + n16, ko)]);
            #pragma unroll
            for (int ct = 0; ct < 2; ++ct)
                bb[ct] = *reinterpret_cast<const bf16x8*>(&Bcur[sw64(wc + ct * 16 + n16, ko)]);
            #pragma unroll
            for (int rt = 0; rt < 4; ++rt)
                #pragma unroll
                for (int ct = 0; ct < 2; ++ct)
                    acc[rt][ct] = __builtin_amdgcn_mfma_f32_16x16x32_bf16(a[rt], bb[ct], acc[rt][ct], 0, 0, 0);
        }
        if (p < 15) store_lds(Anxt, Bnxt);       // vmcnt(0) drain lands here, post-MFMA
    }
    __syncthreads();   // all K-loop LDS traffic done; smem is free for reuse

    // write agg C-tiles into padded Ts
    #pragma unroll
    for (int rt = 0; rt < 4; ++rt)
        #pragma unroll
        for (int ct = 0; ct < 2; ++ct)
            #pragma unroll
            for (int r = 0; r < 4; ++r) {
                int row = wr + rt * 16 + quad * 4 + r, col = wc + ct * 16 + n16;
                Ts[row * TS_LD + col] = (bf16)acc[rt][ct][r];
            }

    // stage Wagg [in][out] transposed -> Wa; W2: LAST? [out][in] direct : transposed
    bf16* Wa = smem;               // 128*128 sw128
    bf16* W2 = smem + 128 * 128;   // 128*128 sw128
    {
        const int c0 = (tid & 15) * 8;
        #pragma unroll
        for (int rr = 0; rr < 4; ++rr) {
            int r = (tid >> 4) * 4 + rr;
            const float4* p = reinterpret_cast<const float4*>(Wagg + r * 128 + c0);
            float4 v0 = p[0], v1 = p[1];
            float vv[8] = {v0.x, v0.y, v0.z, v0.w, v1.x, v1.y, v1.z, v1.w};
            #pragma unroll
            for (int j = 0; j < 8; ++j) {
                int n = c0 + j;
                Wa[n * 128 + (((r >> 3) ^ (n & 15)) << 3) + (r & 7)] = (bf16)vv[j];
            }
        }
    }
    if (LAST) {
        const float4* Wg = reinterpret_cast<const float4*>(W2f);
        #pragma unroll
        for (int i = 0; i < 4; ++i) {
            int g = tid + i * 512, row = g >> 4, gc = g & 15;
            float4 v0 = Wg[2 * g], v1 = Wg[2 * g + 1];
            *reinterpret_cast<bf16x8*>(&W2[row * 128 + ((gc ^ (row & 15)) << 3)]) = cvt8(v0, v1);
        }
    } else {
        const int c0 = (tid & 15) * 8;
        #pragma unroll
        for (int rr = 0; rr < 4; ++rr) {
            int r = (tid >> 4) * 4 + rr;
            const float4* p = reinterpret_cast<const float4*>(W2f + r * 128 + c0);
            float4 v0 = p[0], v1 = p[1];
            float vv[8] = {v0.x, v0.y, v0.z, v0.w, v1.x, v1.y, v1.z, v1.w};
            #pragma unroll
            for (int j = 0; j < 8; ++j) {
                int n = c0 + j;
                W2[n * 128 + (((r >> 3) ^ (n & 15)) << 3) + (r & 7)] = (bf16)vv[j];
            }
        }
    }
    __syncthreads();

    // phase 3: u = relu(agg@Wagg + bagg + m_prev); t = rowscale(u) -> Ts (in place)
    const int rbase = wv * 16;                 // wave = 16 rows x 128 cols
    const size_t growbase = (size_t)b * 1024 + (size_t)mt * 128;
    floatx4 acc2[8];
    #pragma unroll
    for (int c = 0; c < 8; ++c) acc2[c] = (floatx4){0.f, 0.f, 0.f, 0.f};
    #pragma unroll
    for (int kc = 0; kc < 4; ++kc) {
        int k0 = kc * 32 + quad * 8;
        bf16x8 a = *reinterpret_cast<const bf16x8*>(&Ts[(rbase + n16) * TS_LD + k0]);
        #pragma unroll
        for (int ct = 0; ct < 8; ++ct) {
            bf16x8 bb = *reinterpret_cast<const bf16x8*>(&Wa[sw128(ct * 16 + n16, k0)]);
            acc2[ct] = __builtin_amdgcn_mfma_f32_16x16x32_bf16(a, bb, acc2[ct], 0, 0, 0);
        }
    }
    {
        float bva[8];
        #pragma unroll
        for (int ct = 0; ct < 8; ++ct) bva[ct] = bagg[ct * 16 + n16];
        #pragma unroll
        for (int r = 0; r < 4; ++r) {
            int row = rbase + quad * 4 + r;
            size_t grow = growbase + row;
            float u[8], ss = 0.f;
            #pragma unroll
            for (int ct = 0; ct < 8; ++ct) {
                u[ct] = fmaxf(acc2[ct][r] + bva[ct] + (float)Mprev[grow * 128 + ct * 16 + n16], 0.f);
                ss += u[ct] * u[ct];
            }
            #pragma unroll
            for (int off = 1; off < 16; off <<= 1) ss += __shfl_xor(ss, off);
            float sc = hyp_scale(ss);
            #pragma unroll
            for (int ct = 0; ct < 8; ++ct)
                Ts[row * TS_LD + ct * 16 + n16] = (bf16)(u[ct] * sc);
        }
    }
    // same-wave rows only: per-wave DS ordering makes a barrier unnecessary here

    // phase 4: t @ W2 (+b2); LAST: *mask -> fp32 Out; else -> Mout/MTout
    floatx4 acc3[8];
    #pragma unroll
    for (int c = 0; c < 8; ++c) acc3[c] = (floatx4){0.f, 0.f, 0.f, 0.f};
    #pragma unroll
    for (int kc = 0; kc < 4; ++kc) {
        int k0 = kc * 32 + quad * 8;
        bf16x8 a = *reinterpret_cast<const bf16x8*>(&Ts[(rbase + n16) * TS_LD + k0]);
        #pragma unroll
        for (int ct = 0; ct < 8; ++ct) {
            bf16x8 bb = *reinterpret_cast<const bf16x8*>(&W2[sw128(ct * 16 + n16, k0)]);
            acc3[ct] = __builtin_amdgcn_mfma_f32_16x16x32_bf16(a, bb, acc3[ct], 0, 0, 0);
        }
    }
    float bv2[8];
    #pragma unroll
    for (int ct = 0; ct < 8; ++ct) bv2[ct] = b2[ct * 16 + n16];
    #pragma unroll
    for (int r = 0; r < 4; ++r) {
        int row = rbase + quad * 4 + r;
        size_t grow = growbase + row;
        if (LAST) {
            float mk = Mask[grow];
            #pragma unroll
            for (int ct = 0; ct < 8; ++ct)
                Out[grow * 128 + ct * 16 + n16] = (acc3[ct][r] + bv2[ct]) * mk;
        } else {
            #pragma unroll
            for (int ct = 0; ct < 8; ++ct) {
                bf16 o = (bf16)(acc3[ct][r] + bv2[ct]);
                Mout[grow * 128 + ct * 16 + n16] = o;
                MTout[((grow >> 10) * 128 + ct * 16 + n16) * 1024 + (grow & 1023)] = o;
            }
        }
    }
}

extern "C" void kernel_launch(void* const* d_in, const int* in_sizes, int n_in,
                              void* d_out, int out_size, void* d_ws, size_t ws_size,
                              hipStream_t stream)
{
    const float* X    = (const float*)d_in[0];   // [32,1024,128]
    const float* Adj  = (const float*)d_in[1];   // [32,1024,1024]
    const float* Mask = (const float*)d_in[2];   // [32,1024,1]
    const float* Wemb = (const float*)d_in[3];   // [128,128] (out,in)
    const float* Wmsg = (const float*)d_in[4];   // [2,128,128] (in,out)
    const float* bmsg = (const float*)d_in[5];   // [2,128]
    const float* Wagg = (const float*)d_in[6];   // [2,128,128] (in,out)
    const float* bagg = (const float*)d_in[7];   // [2,128]
    const float* Wprj = (const float*)d_in[8];   // [128,128] (out,in)
    const float* bprj = (const float*)d_in[9];   // [128]
    float* out = (float*)d_out;

    const size_t BN = 32768;
    bf16* m0  = (bf16*)d_ws;         // [BN,128]
    bf16* m0T = m0  + BN * 128;      // [32,128,1024]
    bf16* m1  = m0T + BN * 128;      // [BN,128]
    bf16* m1T = m1  + BN * 128;      // [32,128,1024]

    embed_msg<<<256, 256, 0, stream>>>(X, Wemb, Wmsg, bmsg, m0, m0T);
    adj_fused<0><<<256, 512, 0, stream>>>(Adj, m0T, m0, Wagg, bagg,
                                          Wmsg + 16384, bmsg + 128, nullptr,
                                          m1, m1T, nullptr);
    adj_fused<1><<<256, 512, 0, stream>>>(Adj, m1T, m1, Wagg + 16384, bagg + 128,
                                          Wprj, bprj, Mask,
                                          nullptr, nullptr, out);
}